// Round 6
// baseline (755.811 us; speedup 1.0000x reference)
//
#include <hip/hip_runtime.h>

// SimpleRNN: h_{t+1} = tanh(h_t @ H^T + x_t @ U + b); out = h_T @ A^T + c
// T=512 B=2048 IN=28 HID=198 OUT=10, all fp32.
//
// R6: persistent kernel, grid=256 (1 block/CU), BB=8 batch rows/block,
// 512 threads = 8 waves = 2 waves/SIMD.
// Waves 0-6: compute, TWO 16-col N-tiles each (14 tiles, 13 real) -> one
// ds_read_b128 of the A-fragment feeds 4 MFMAs (2 tiles x hi/lo pass).
// LDS read burst: 56 x b128 per step per CU (was 104 with 13 x 1-tile waves).
// Wave 7: x-stager (packs x[t+1] hi/lo A-frag into LDS slot kt=7).
//
// hi/lo-packed M: A rows 0-7 = h_hi, rows 8-15 = h_lo; 2 MFMA passes
// (Bhi, Blo), fold C[r]+C[r+8] via v_permlane32_swap -> exact
// (hi+lo)*(Bhi+Blo). x@U folded as K-slot 7 with B=U.
// tanh = 1 - 2*rcp(exp2(2*log2e*x)+1). One __syncthreads per step.

#define T_STEPS 512
#define BATCH   2048
#define IN_DIM  28
#define HID     198
#define OUT_DIM 10
#define BB      8    // batch rows per block
#define KT      8    // 7 H k-tiles (224 >= 198) + 1 U/x slot
#define QT      2    // N-tiles per compute wave

typedef __attribute__((ext_vector_type(8))) __bf16 bf16x8;
typedef __attribute__((ext_vector_type(4))) float  floatx4;

__device__ __forceinline__ floatx4 mfma16(bf16x8 a, bf16x8 b, floatx4 c) {
    return __builtin_amdgcn_mfma_f32_16x16x32_bf16(a, b, c, 0, 0, 0);
}

// tanh(x) = 1 - 2/(exp(2x)+1); exp2-based, saturates via IEEE inf/0.
__device__ __forceinline__ float fast_tanh(float x) {
    float e = __builtin_amdgcn_exp2f(x * 2.885390081777926357f); // exp(2x)
    float r = __builtin_amdgcn_rcpf(e + 1.0f);
    return __builtin_fmaf(-2.0f, r, 1.0f);
}

// s[lane] + s[lane^32] in every lane (VALU, not LDS pipe).
__device__ __forceinline__ float fold32(float s, int lane) {
#if defined(__has_builtin) && __has_builtin(__builtin_amdgcn_permlane32_swap)
    int si = __float_as_int(s);
    auto pq = __builtin_amdgcn_permlane32_swap(si, si, false, false);
    return __int_as_float(pq[0]) + __int_as_float(pq[1]);
#else
    return s + __shfl(s, lane ^ 32, 64);
#endif
}

__global__ void __launch_bounds__(512, 2)
rnn_kernel(const float* __restrict__ x, const float* __restrict__ H,
           const float* __restrict__ U, const float* __restrict__ A,
           const float* __restrict__ bvec, const float* __restrict__ cvec,
           float* __restrict__ out)
{
    // A-frag ping-pong: [buf][kt][lane][idx]; lane = qt*16 + arow,
    // arow 0-7 = h_hi(batch row arow), 8-15 = h_lo(batch row arow-8).
    // Slot kt=7 holds the x fragment (written by the stager wave).
    __shared__ __align__(16) __bf16 lds_A[2][KT][64][8];   // 16 KB
    __shared__ float lds_h[BB][204];                        // final h, fp32

    const int tid  = threadIdx.x;
    const int lane = tid & 63;
    const int wv   = tid >> 6;          // wave id 0..7
    const int m    = lane & 15;         // A-row / C-col index within tile
    const int quad = lane >> 4;         // 0..3
    const int b0   = blockIdx.x * BB;

    // zero-init H-slots (kt 0..6) of both buffers: h0 = 0; phantom K rows
    // stay 0 forever (epilogue never writes k >= 198).
    {
        __bf16* p0 = &lds_A[0][0][0][0];
        __bf16* p1 = &lds_A[1][0][0][0];
        for (int i = tid; i < 7*64*8; i += 512) { p0[i] = (__bf16)0.0f; p1[i] = (__bf16)0.0f; }
    }

    const int r8    = m & 7;
    const bool isLo = (m >= 8);

    // ---- compute-wave setup: stationary B fragments + epilogue indices ----
    bf16x8 Bhi[QT][KT], Blo[QT][KT];
    float  bias_eff[QT] = {0.0f, 0.0f};
    int    jcol[QT] = {0,0}, e_ktd[QT] = {0,0}, e_rowb[QT] = {0,0}, e_idx[QT] = {0,0};
    bool   e_wr[QT] = {false, false};
    if (wv < 7) {
        #pragma unroll
        for (int q = 0; q < QT; ++q) {
            const int j = (wv*QT + q)*16 + m;           // output column (>=198 phantom)
            jcol[q] = j;
            bias_eff[q] = (j < HID && quad < 2) ? bvec[j] : 0.0f;
            #pragma unroll
            for (int kt = 0; kt < 7; ++kt) {
                bf16x8 hi8, lo8;
                #pragma unroll
                for (int idx = 0; idx < 8; ++idx) {
                    int k = kt*32 + quad*8 + idx;
                    float v = (j < HID && k < HID) ? H[j*HID + k] : 0.0f;  // B[k][j]=H[j][k]
                    __bf16 h = (__bf16)v;
                    hi8[idx] = h;
                    lo8[idx] = (__bf16)(v - (float)h);
                }
                Bhi[q][kt] = hi8; Blo[q][kt] = lo8;
            }
            {   // slot 7: U
                bf16x8 uh, ul;
                #pragma unroll
                for (int idx = 0; idx < 8; ++idx) {
                    int i = quad*8 + idx;
                    float v = (j < HID && i < IN_DIM) ? U[i*HID + j] : 0.0f;
                    __bf16 h = (__bf16)v;
                    uh[idx] = h;
                    ul[idx] = (__bf16)(v - (float)h);
                }
                Bhi[q][7] = uh; Blo[q][7] = ul;
            }
            e_ktd[q]  = j >> 5;
            e_rowb[q] = ((j & 31) >> 3)*16 + quad*4;   // + reg gives the A-row slot
            e_idx[q]  = j & 7;
            e_wr[q]   = (j < HID);
        }
    }

    // ---- stager-wave setup: pack x[0] into slot 7 of buffer 0 ----
    const float* xrow = x + (size_t)(b0 + r8) * IN_DIM + quad*8;
    const size_t tstride = (size_t)BATCH * IN_DIM;
    floatx4 zero4 = {0.0f, 0.0f, 0.0f, 0.0f};
    if (wv == 7) {
        floatx4 f0 = *(const floatx4*)xrow;
        floatx4 f1 = (quad < 3) ? *(const floatx4*)(xrow + 4) : zero4;
        float xv[8] = {f0[0],f0[1],f0[2],f0[3], f1[0],f1[1],f1[2],f1[3]};
        bf16x8 ax;
        #pragma unroll
        for (int i = 0; i < 8; ++i) {
            __bf16 h = (__bf16)xv[i];
            ax[i] = isLo ? (__bf16)(xv[i] - (float)h) : h;
        }
        *(bf16x8*)&lds_A[0][7][lane][0] = ax;
    }

    // ================= time loop =================
    #pragma unroll 1
    for (int t = 0; t < T_STEPS; ++t) {
        const int rb = t & 1;
        const int wb = rb ^ 1;

        __syncthreads();   // all prior writes into rb visible; wb free to write

        if (wv < 7) {
            floatx4 acc1[QT], acc2[QT];
            #pragma unroll
            for (int q = 0; q < QT; ++q) {
                acc1[q] = (floatx4){bias_eff[q], bias_eff[q], bias_eff[q], bias_eff[q]};
                acc2[q] = zero4;
            }
            #pragma unroll
            for (int kt = 0; kt < KT; ++kt) {
                bf16x8 a = *(const bf16x8*)&lds_A[rb][kt][lane][0];  // shared by both tiles
                acc1[0] = mfma16(a, Bhi[0][kt], acc1[0]);
                acc2[0] = mfma16(a, Blo[0][kt], acc2[0]);
                acc1[1] = mfma16(a, Bhi[1][kt], acc1[1]);
                acc2[1] = mfma16(a, Blo[1][kt], acc2[1]);
            }
            // fold hi/lo halves + tanh (all lanes; phantom cols give tanh(0)=0),
            // then guarded scatter of hi (quads 0,1) / lo (quads 2,3) bf16.
            #pragma unroll
            for (int q = 0; q < QT; ++q) {
                #pragma unroll
                for (int reg = 0; reg < 4; ++reg) {
                    float v  = fast_tanh(fold32(acc1[q][reg] + acc2[q][reg], lane));
                    __bf16 h = (__bf16)v;
                    __bf16 wval = (quad < 2) ? h : (__bf16)(v - (float)h);
                    if (e_wr[q]) {
                        lds_A[wb][e_ktd[q]][e_rowb[q] + reg][e_idx[q]] = wval;
                        if (t == T_STEPS - 1 && quad < 2) lds_h[quad*4 + reg][jcol[q]] = v;
                    }
                }
            }
        } else {
            // stage x[t+1] into slot 7 of wb
            const int tn = (t + 1 < T_STEPS) ? (t + 1) : t;
            const float* p = xrow + (size_t)tn * tstride;
            floatx4 f0 = *(const floatx4*)p;
            floatx4 f1 = (quad < 3) ? *(const floatx4*)(p + 4) : zero4;
            float xv[8] = {f0[0],f0[1],f0[2],f0[3], f1[0],f1[1],f1[2],f1[3]};
            bf16x8 ax;
            #pragma unroll
            for (int i = 0; i < 8; ++i) {
                __bf16 h = (__bf16)xv[i];
                ax[i] = isLo ? (__bf16)(xv[i] - (float)h) : h;
            }
            *(bf16x8*)&lds_A[wb][7][lane][0] = ax;
        }
    }

    __syncthreads();

    // ---- output: out[b][o] = sum_k h[b][k]*A[o][k] + c[o] (tiny, scalar) ----
    if (tid < BB * OUT_DIM) {
        const int r = tid / OUT_DIM;
        const int o = tid % OUT_DIM;
        float s = cvec[o];
        for (int k = 0; k < HID; ++k) s += lds_h[r][k] * A[o*HID + k];
        out[(size_t)(b0 + r) * OUT_DIM + o] = s;
    }
}

extern "C" void kernel_launch(void* const* d_in, const int* in_sizes, int n_in,
                              void* d_out, int out_size, void* d_ws, size_t ws_size,
                              hipStream_t stream) {
    const float* x  = (const float*)d_in[0];
    const float* H  = (const float*)d_in[1];
    const float* U  = (const float*)d_in[2];
    const float* A  = (const float*)d_in[3];
    const float* b  = (const float*)d_in[4];
    const float* c  = (const float*)d_in[5];
    float* out = (float*)d_out;

    rnn_kernel<<<dim3(BATCH / BB), dim3(512), 0, stream>>>(x, H, U, A, b, c, out);
}